// Round 7
// baseline (148.378 us; speedup 1.0000x reference)
//
#include <hip/hip_runtime.h>

typedef float f32x4 __attribute__((ext_vector_type(4)));
typedef short bf16x8 __attribute__((ext_vector_type(8)));

#define MFMA16 __builtin_amdgcn_mfma_f32_16x16x32_bf16

// ---------- bf16 helpers (manual RNE, verified rounds 2-6) ----------
__device__ __forceinline__ unsigned short f2bf(float f) {
    union { float f; unsigned int i; } x;
    x.f = f;
    unsigned int i = x.i;
    unsigned int lsb = (i >> 16) & 1u;
    i += 0x7FFFu + lsb;
    return (unsigned short)(i >> 16);
}
__device__ __forceinline__ bf16x8 cvt8(float4 a, float4 b) {
    union { bf16x8 v; unsigned short u[8]; } r;
    r.u[0] = f2bf(a.x); r.u[1] = f2bf(a.y); r.u[2] = f2bf(a.z); r.u[3] = f2bf(a.w);
    r.u[4] = f2bf(b.x); r.u[5] = f2bf(b.y); r.u[6] = f2bf(b.z); r.u[7] = f2bf(b.w);
    return r.v;
}

// ws layout (bytes):
//   0         : WqkvT bf16 [768][256]      (393216)
//   393216    : WoutT bf16 [256][256]      (131072)
//   524288    : bias_tab f32 [64][64]      (16384)
//   540672    : QKV bf16, per window-head (wh = wid*8+h), 12288 B each:
//               Q[64][32] @0, K[64][32] @4096, VT[32][64] @8192
#define WS_NEED        540672
#define WS3_NEED       101203968
#define WOUTT_SHORT_OFF 196608
#define QKV_SHORT_OFF   270336

// =====================================================================
// Prep: transpose weights to bf16 n-major; expand PE to [q][j] table.
// =====================================================================
__global__ void prep_kernel(const float* __restrict__ wqkv,
                            const float* __restrict__ wout,
                            const float* __restrict__ pe,
                            unsigned short* __restrict__ wsT,
                            float* __restrict__ bias_tab)
{
    const int b = blockIdx.x, tid = threadIdx.x;
    if (b < 256) {
        const int w = tid >> 6, l = tid & 63;
        const int r = b * 4 + w;               // output row (n)
        const float* src;
        unsigned short* dst;
        int stride;
        if (r < 768) { src = wqkv + r; stride = 768; dst = wsT + (size_t)r * 256; }
        else { int n = r - 768; src = wout + n; stride = 256;
               dst = wsT + WOUTT_SHORT_OFF + (size_t)n * 256; }
        ushort4 v;
        v.x = f2bf(src[(size_t)(l * 4 + 0) * stride]);
        v.y = f2bf(src[(size_t)(l * 4 + 1) * stride]);
        v.z = f2bf(src[(size_t)(l * 4 + 2) * stride]);
        v.w = f2bf(src[(size_t)(l * 4 + 3) * stride]);
        *reinterpret_cast<ushort4*>(dst + l * 4) = v;
    } else {
        #pragma unroll
        for (int i = 0; i < 16; ++i) {
            int idx = tid + i * 256;           // q*64 + j
            int q = idx >> 6, j = idx & 63;
            int dy = (j >> 3) - (q >> 3) + 7;
            int dx = (j & 7) - (q & 7) + 7;
            bias_tab[idx] = pe[dy * 15 + dx];
        }
    }
}

// =====================================================================
// qkv_gemm: grid 1024 (1 block per window), 256 thr (4 waves).
// X staged once; 3 passes (pass = matrix Q/K/V); wave = heads 2wv,2wv+1
// of that matrix (64 cols), acc[4 m][4 n], direct-global B + prefetch.
// Epilogue writes attention-ready bf16 into ws:
//   Q (scaled), K as [tok][32] via wave-private LDS bounce;
//   V as VT[ch][tok] directly (ushort4 pack).
// LDS 43008 B -> 3 blocks/CU. No barriers after the X stage.
// =====================================================================
__global__ __launch_bounds__(256, 3)
void qkv_gemm(const float* __restrict__ x,
              const unsigned short* __restrict__ wqkvT,
              unsigned short* __restrict__ qkv)
{
    __shared__ __align__(16) unsigned short sX[64][264];
    __shared__ __align__(16) unsigned short sB[4][16][72];  // wave-private bounce

    const int tid  = threadIdx.x;
    const int lane = tid & 63;
    const int wv   = tid >> 6;
    const int ln   = lane & 15;
    const int lg   = lane >> 4;

    const int wid = blockIdx.x;
    const int blw = wid >> 6;
    const int whr = (wid >> 3) & 7;
    const int wwc = wid & 7;
    const int tok_base = blw * 4096 + whr * 512 + wwc * 8;
    // token(i) = tok_base + (i>>3)*64 + (i&7)

    // ---- stage X once (64 x 256 f32 -> bf16) ----
    #pragma unroll
    for (int it = 0; it < 8; ++it) {
        int idx = tid + (it << 8);
        int row = idx >> 5, c8 = idx & 31;
        int tok = tok_base + ((row >> 3) << 6) + (row & 7);
        const float* p = x + (size_t)tok * 256 + c8 * 8;
        float4 a = *reinterpret_cast<const float4*>(p);
        float4 b = *reinterpret_cast<const float4*>(p + 4);
        *reinterpret_cast<bf16x8*>(&sX[row][c8 * 8]) = cvt8(a, b);
    }
    __syncthreads();

    const float scale = 0.17677669529663687f;

    for (int p = 0; p < 3; ++p) {
        // B pointers: rows n = p*256 + wv*64 + j*16 + ln of WqkvT
        const unsigned short* b0 =
            wqkvT + (size_t)(p * 256 + wv * 64 + ln) * 256 + lg * 8;
        const unsigned short* b1 = b0 + 16 * 256;
        const unsigned short* b2 = b0 + 32 * 256;
        const unsigned short* b3 = b0 + 48 * 256;
        bf16x8 bc0 = *reinterpret_cast<const bf16x8*>(b0);
        bf16x8 bc1 = *reinterpret_cast<const bf16x8*>(b1);
        bf16x8 bc2 = *reinterpret_cast<const bf16x8*>(b2);
        bf16x8 bc3 = *reinterpret_cast<const bf16x8*>(b3);

        f32x4 acc[4][4];
        #pragma unroll
        for (int m = 0; m < 4; ++m)
            #pragma unroll
            for (int j = 0; j < 4; ++j) acc[m][j] = (f32x4)(0.f);

        #pragma unroll
        for (int st = 0; st < 8; ++st) {
            const int ko = st * 32 + lg * 8;
            bf16x8 a0 = *reinterpret_cast<const bf16x8*>(&sX[     ln][ko]);
            bf16x8 a1 = *reinterpret_cast<const bf16x8*>(&sX[16 + ln][ko]);
            bf16x8 a2 = *reinterpret_cast<const bf16x8*>(&sX[32 + ln][ko]);
            bf16x8 a3 = *reinterpret_cast<const bf16x8*>(&sX[48 + ln][ko]);
            bf16x8 bn0 = bc0, bn1 = bc1, bn2 = bc2, bn3 = bc3;
            if (st < 7) {
                bn0 = *reinterpret_cast<const bf16x8*>(b0 + (st + 1) * 32);
                bn1 = *reinterpret_cast<const bf16x8*>(b1 + (st + 1) * 32);
                bn2 = *reinterpret_cast<const bf16x8*>(b2 + (st + 1) * 32);
                bn3 = *reinterpret_cast<const bf16x8*>(b3 + (st + 1) * 32);
            }
            acc[0][0] = MFMA16(a0, bc0, acc[0][0], 0, 0, 0);
            acc[1][0] = MFMA16(a1, bc0, acc[1][0], 0, 0, 0);
            acc[2][0] = MFMA16(a2, bc0, acc[2][0], 0, 0, 0);
            acc[3][0] = MFMA16(a3, bc0, acc[3][0], 0, 0, 0);
            acc[0][1] = MFMA16(a0, bc1, acc[0][1], 0, 0, 0);
            acc[1][1] = MFMA16(a1, bc1, acc[1][1], 0, 0, 0);
            acc[2][1] = MFMA16(a2, bc1, acc[2][1], 0, 0, 0);
            acc[3][1] = MFMA16(a3, bc1, acc[3][1], 0, 0, 0);
            acc[0][2] = MFMA16(a0, bc2, acc[0][2], 0, 0, 0);
            acc[1][2] = MFMA16(a1, bc2, acc[1][2], 0, 0, 0);
            acc[2][2] = MFMA16(a2, bc2, acc[2][2], 0, 0, 0);
            acc[3][2] = MFMA16(a3, bc2, acc[3][2], 0, 0, 0);
            acc[0][3] = MFMA16(a0, bc3, acc[0][3], 0, 0, 0);
            acc[1][3] = MFMA16(a1, bc3, acc[1][3], 0, 0, 0);
            acc[2][3] = MFMA16(a2, bc3, acc[2][3], 0, 0, 0);
            acc[3][3] = MFMA16(a3, bc3, acc[3][3], 0, 0, 0);
            bc0 = bn0; bc1 = bn1; bc2 = bn2; bc3 = bn3;
        }

        if (p < 2) {
            // Q/K: bounce each m-tile (16 tok x 64 cols) through wave-
            // private LDS, then coalesced copy to [tok][32] per head.
            const float sc = (p == 0) ? scale : 1.0f;
            const int tl  = lane >> 2;            // local token 0..15
            const int cq  = lane & 3;             // col quarter
            const int head = 2 * wv + (cq >> 1);
            const int ch0  = (cq & 1) * 16;
            const size_t wh = (size_t)wid * 8 + head;
            unsigned short* dbase =
                qkv + wh * 6144 + (size_t)p * 2048 + ch0;
            #pragma unroll
            for (int m = 0; m < 4; ++m) {
                #pragma unroll
                for (int j = 0; j < 4; ++j)
                    #pragma unroll
                    for (int r = 0; r < 4; ++r)
                        sB[wv][lg * 4 + r][j * 16 + ln] =
                            f2bf(acc[m][j][r] * sc);
                // wave-private RAW: compiler inserts lgkmcnt
                bf16x8 v0 = *reinterpret_cast<const bf16x8*>(&sB[wv][tl][cq * 16]);
                bf16x8 v1 = *reinterpret_cast<const bf16x8*>(&sB[wv][tl][cq * 16 + 8]);
                unsigned short* dst = dbase + (size_t)(m * 16 + tl) * 32;
                *reinterpret_cast<bf16x8*>(dst)     = v0;
                *reinterpret_cast<bf16x8*>(dst + 8) = v1;
            }
        } else {
            // V: direct transposed writes VT[ch][tok]
            #pragma unroll
            for (int j = 0; j < 4; ++j) {
                const int head = 2 * wv + (j >> 1);
                const int ch   = (j & 1) * 16 + ln;
                const size_t wh = (size_t)wid * 8 + head;
                unsigned short* vbase = qkv + wh * 6144 + 4096 + (size_t)ch * 64;
                #pragma unroll
                for (int m = 0; m < 4; ++m) {
                    ushort4 pv;
                    pv.x = f2bf(acc[m][j][0]); pv.y = f2bf(acc[m][j][1]);
                    pv.z = f2bf(acc[m][j][2]); pv.w = f2bf(acc[m][j][3]);
                    *reinterpret_cast<ushort4*>(vbase + m * 16 + lg * 4) = pv;
                }
            }
        }
    }
}

// =====================================================================
// attn5: grid 8192 (1 block per window-head), 256 thr (4 waves),
// wave = 16 queries. All MFMA fragments read directly from the
// attention-ready ws layouts (L2/L3-hot). LDS: only per-wave P (9.2 KB).
// =====================================================================
__global__ __launch_bounds__(256, 4)
void attn5(const unsigned short* __restrict__ qkv,
           const float* __restrict__ bias_tab,
           float* __restrict__ out)
{
    __shared__ __align__(16) unsigned short sP[4][16][72];

    const int tid  = threadIdx.x;
    const int lane = tid & 63;
    const int wv   = tid >> 6;
    const int ln   = lane & 15;
    const int lg   = lane >> 4;

    const int h   = blockIdx.x & 7;
    const int wid = blockIdx.x >> 3;
    const int blw = wid >> 6;
    const int whr = (wid >> 3) & 7;
    const int wwc = wid & 7;
    const int tok_base = blw * 4096 + whr * 512 + wwc * 8;

    const unsigned short* base = qkv + (size_t)blockIdx.x * 6144;
    const unsigned short* Kb   = base + 2048;
    const unsigned short* VTb  = base + 4096;

    const int q = wv * 16 + ln;
    bf16x8 qf = *reinterpret_cast<const bf16x8*>(base + (size_t)q * 32 + lg * 8);

    f32x4 st[4];
    #pragma unroll
    for (int mt = 0; mt < 4; ++mt) {
        bf16x8 kf = *reinterpret_cast<const bf16x8*>(
            Kb + (size_t)(mt * 16 + ln) * 32 + lg * 8);
        st[mt] = MFMA16(kf, qf, (f32x4)(0.f), 0, 0, 0);
    }

    float sv[16];
    float mx = -3.0e38f;
    #pragma unroll
    for (int mt = 0; mt < 4; ++mt) {
        float4 bt = *reinterpret_cast<const float4*>(
            &bias_tab[q * 64 + mt * 16 + lg * 4]);
        float b4[4] = {bt.x, bt.y, bt.z, bt.w};
        #pragma unroll
        for (int r = 0; r < 4; ++r) {
            float s = st[mt][r] + b4[r];
            sv[mt * 4 + r] = s;
            mx = fmaxf(mx, s);
        }
    }
    mx = fmaxf(mx, __shfl_xor(mx, 16));
    mx = fmaxf(mx, __shfl_xor(mx, 32));
    float sum = 0.f;
    #pragma unroll
    for (int i = 0; i < 16; ++i) { sv[i] = __expf(sv[i] - mx); sum += sv[i]; }
    sum += __shfl_xor(sum, 16);
    sum += __shfl_xor(sum, 32);
    const float inv = 1.0f / sum;

    #pragma unroll
    for (int mt = 0; mt < 4; ++mt) {
        ushort4 pv;
        pv.x = f2bf(sv[mt * 4 + 0] * inv);
        pv.y = f2bf(sv[mt * 4 + 1] * inv);
        pv.z = f2bf(sv[mt * 4 + 2] * inv);
        pv.w = f2bf(sv[mt * 4 + 3] * inv);
        *reinterpret_cast<ushort4*>(&sP[wv][ln][mt * 16 + lg * 4]) = pv;
    }

    f32x4 o[2] = {(f32x4)(0.f), (f32x4)(0.f)};
    #pragma unroll
    for (int ks = 0; ks < 2; ++ks) {
        bf16x8 pf = *reinterpret_cast<const bf16x8*>(&sP[wv][ln][ks * 32 + lg * 8]);
        #pragma unroll
        for (int nt = 0; nt < 2; ++nt) {
            bf16x8 vf = *reinterpret_cast<const bf16x8*>(
                VTb + (size_t)(nt * 16 + ln) * 64 + ks * 32 + lg * 8);
            o[nt] = MFMA16(pf, vf, o[nt], 0, 0, 0);
        }
    }

    #pragma unroll
    for (int nt = 0; nt < 2; ++nt) {
        #pragma unroll
        for (int r = 0; r < 4; ++r) {
            int qi  = wv * 16 + lg * 4 + r;
            int tok = tok_base + ((qi >> 3) << 6) + (qi & 7);
            out[(size_t)tok * 256 + h * 32 + nt * 16 + ln] = o[nt][r];
        }
    }
}

// =====================================================================
// winattn4: fused fallback path (verified round 6) if ws < WS3_NEED.
// =====================================================================
__global__ __launch_bounds__(256, 3)
void winattn4(const float* __restrict__ x,
              const unsigned short* __restrict__ wqkvT,
              const float* __restrict__ bias_tab,
              float* __restrict__ out)
{
    __shared__ __align__(16) unsigned char smem[38912];
    typedef unsigned short (*arr264)[264];
    typedef unsigned short (*arr72)[72];
    typedef unsigned short (*arr40)[40];
    arr264 sX = reinterpret_cast<arr264>(smem);
    arr40 sQ  = reinterpret_cast<arr40>(smem);
    arr40 sK  = reinterpret_cast<arr40>(smem + 10240);
    arr72 sVT = reinterpret_cast<arr72>(smem + 20480);
    arr72 sP  = reinterpret_cast<arr72>(smem + 29696);

    const int tid  = threadIdx.x;
    const int lane = tid & 63;
    const int wv   = tid >> 6;
    const int ln   = lane & 15;
    const int lg   = lane >> 4;

    const int L   = ((blockIdx.x & 7) << 9) + (blockIdx.x >> 3);
    const int wid = L >> 2;
    const int h0  = (L & 3) << 1;
    const int blw = wid >> 6;
    const int whr = (wid >> 3) & 7;
    const int wwc = wid & 7;
    const int tok_base = blw * 4096 + whr * 512 + wwc * 8;

    const int hp_own = wv >> 1;
    const int hf_own = wv & 1;
    const unsigned short* bq = wqkvT +
        (size_t)((h0 + hp_own) * 32 + hf_own * 16 + ln) * 256 + lg * 8;
    const unsigned short* bk = bq + 256 * 256;
    const unsigned short* bv = bk + 256 * 256;
    bf16x8 bc0 = *reinterpret_cast<const bf16x8*>(bq);
    bf16x8 bc1 = *reinterpret_cast<const bf16x8*>(bk);
    bf16x8 bc2 = *reinterpret_cast<const bf16x8*>(bv);

    #pragma unroll
    for (int it = 0; it < 8; ++it) {
        int idx = tid + (it << 8);
        int row = idx >> 5, c8 = idx & 31;
        int tok = tok_base + ((row >> 3) << 6) + (row & 7);
        const float* p = x + (size_t)tok * 256 + c8 * 8;
        float4 a = *reinterpret_cast<const float4*>(p);
        float4 b = *reinterpret_cast<const float4*>(p + 4);
        *reinterpret_cast<bf16x8*>(&sX[row][c8 * 8]) = cvt8(a, b);
    }
    __syncthreads();

    f32x4 acc[4][3];
    #pragma unroll
    for (int m = 0; m < 4; ++m)
        #pragma unroll
        for (int t = 0; t < 3; ++t) acc[m][t] = (f32x4)(0.f);

    #pragma unroll
    for (int st = 0; st < 8; ++st) {
        const int ko = st * 32 + lg * 8;
        bf16x8 a0 = *reinterpret_cast<const bf16x8*>(&sX[     ln][ko]);
        bf16x8 a1 = *reinterpret_cast<const bf16x8*>(&sX[16 + ln][ko]);
        bf16x8 a2 = *reinterpret_cast<const bf16x8*>(&sX[32 + ln][ko]);
        bf16x8 a3 = *reinterpret_cast<const bf16x8*>(&sX[48 + ln][ko]);
        bf16x8 bn0 = bc0, bn1 = bc1, bn2 = bc2;
        if (st < 7) {
            bn0 = *reinterpret_cast<const bf16x8*>(bq + (st + 1) * 32);
            bn1 = *reinterpret_cast<const bf16x8*>(bk + (st + 1) * 32);
            bn2 = *reinterpret_cast<const bf16x8*>(bv + (st + 1) * 32);
        }
        acc[0][0] = MFMA16(a0, bc0, acc[0][0], 0, 0, 0);
        acc[1][0] = MFMA16(a1, bc0, acc[1][0], 0, 0, 0);
        acc[2][0] = MFMA16(a2, bc0, acc[2][0], 0, 0, 0);
        acc[3][0] = MFMA16(a3, bc0, acc[3][0], 0, 0, 0);
        acc[0][1] = MFMA16(a0, bc1, acc[0][1], 0, 0, 0);
        acc[1][1] = MFMA16(a1, bc1, acc[1][1], 0, 0, 0);
        acc[2][1] = MFMA16(a2, bc1, acc[2][1], 0, 0, 0);
        acc[3][1] = MFMA16(a3, bc1, acc[3][1], 0, 0, 0);
        acc[0][2] = MFMA16(a0, bc2, acc[0][2], 0, 0, 0);
        acc[1][2] = MFMA16(a1, bc2, acc[1][2], 0, 0, 0);
        acc[2][2] = MFMA16(a2, bc2, acc[2][2], 0, 0, 0);
        acc[3][2] = MFMA16(a3, bc2, acc[3][2], 0, 0, 0);
        bc0 = bn0; bc1 = bn1; bc2 = bn2;
    }
    __syncthreads();

    const float scale = 0.17677669529663687f;
    #pragma unroll
    for (int m = 0; m < 4; ++m) {
        #pragma unroll
        for (int r = 0; r < 4; ++r)
            sQ[hp_own * 64 + m * 16 + lg * 4 + r][hf_own * 16 + ln] =
                f2bf(acc[m][0][r] * scale);
        #pragma unroll
        for (int r = 0; r < 4; ++r)
            sK[hp_own * 64 + m * 16 + lg * 4 + r][hf_own * 16 + ln] =
                f2bf(acc[m][1][r]);
        ushort4 pv;
        pv.x = f2bf(acc[m][2][0]); pv.y = f2bf(acc[m][2][1]);
        pv.z = f2bf(acc[m][2][2]); pv.w = f2bf(acc[m][2][3]);
        *reinterpret_cast<ushort4*>(
            &sVT[hp_own * 32 + hf_own * 16 + ln][m * 16 + lg * 4]) = pv;
    }
    __syncthreads();

    const int q = wv * 16 + ln;
    #pragma unroll
    for (int hp = 0; hp < 2; ++hp) {
        bf16x8 qf = *reinterpret_cast<const bf16x8*>(&sQ[hp * 64 + q][lg * 8]);
        f32x4 st[4];
        #pragma unroll
        for (int mt = 0; mt < 4; ++mt) {
            bf16x8 kf = *reinterpret_cast<const bf16x8*>(
                &sK[hp * 64 + mt * 16 + ln][lg * 8]);
            st[mt] = MFMA16(kf, qf, (f32x4)(0.f), 0, 0, 0);
        }

        float sv[16];
        float mx = -3.0e38f;
        #pragma unroll
        for (int mt = 0; mt < 4; ++mt) {
            float4 bt = *reinterpret_cast<const float4*>(
                &bias_tab[q * 64 + mt * 16 + lg * 4]);
            float b4[4] = {bt.x, bt.y, bt.z, bt.w};
            #pragma unroll
            for (int r = 0; r < 4; ++r) {
                float s = st[mt][r] + b4[r];
                sv[mt * 4 + r] = s;
                mx = fmaxf(mx, s);
            }
        }
        mx = fmaxf(mx, __shfl_xor(mx, 16));
        mx = fmaxf(mx, __shfl_xor(mx, 32));
        float sum = 0.f;
        #pragma unroll
        for (int i = 0; i < 16; ++i) { sv[i] = __expf(sv[i] - mx); sum += sv[i]; }
        sum += __shfl_xor(sum, 16);
        sum += __shfl_xor(sum, 32);
        const float inv = 1.0f / sum;

        #pragma unroll
        for (int mt = 0; mt < 4; ++mt) {
            ushort4 pv;
            pv.x = f2bf(sv[mt * 4 + 0] * inv);
            pv.y = f2bf(sv[mt * 4 + 1] * inv);
            pv.z = f2bf(sv[mt * 4 + 2] * inv);
            pv.w = f2bf(sv[mt * 4 + 3] * inv);
            *reinterpret_cast<ushort4*>(&sP[wv * 16 + ln][mt * 16 + lg * 4]) = pv;
        }

        f32x4 o[2] = {(f32x4)(0.f), (f32x4)(0.f)};
        #pragma unroll
        for (int ks = 0; ks < 2; ++ks) {
            bf16x8 pf = *reinterpret_cast<const bf16x8*>(
                &sP[wv * 16 + ln][ks * 32 + lg * 8]);
            #pragma unroll
            for (int nt = 0; nt < 2; ++nt) {
                bf16x8 vf = *reinterpret_cast<const bf16x8*>(
                    &sVT[hp * 32 + nt * 16 + ln][ks * 32 + lg * 8]);
                o[nt] = MFMA16(pf, vf, o[nt], 0, 0, 0);
            }
        }

        #pragma unroll
        for (int nt = 0; nt < 2; ++nt) {
            #pragma unroll
            for (int r = 0; r < 4; ++r) {
                int qi  = wv * 16 + lg * 4 + r;
                int tok = tok_base + ((qi >> 3) << 6) + (qi & 7);
                out[(size_t)tok * 256 + (h0 + hp) * 32 + nt * 16 + ln] = o[nt][r];
            }
        }
    }
}

// =====================================================================
// proj4: in-place out = A @ w_out + b_out (verified, near write-floor).
// =====================================================================
__global__ __launch_bounds__(256, 3)
void proj4(float* __restrict__ io,
           const unsigned short* __restrict__ woutT,
           const float* __restrict__ b_out)
{
    __shared__ __align__(16) unsigned short sA[64][264];

    const int tid  = threadIdx.x;
    const int lane = tid & 63;
    const int wv   = tid >> 6;
    const int ln   = lane & 15;
    const int lg   = lane >> 4;
    const size_t m0 = (size_t)blockIdx.x * 64;

    const unsigned short* b0 = woutT + (size_t)((wv +  0) * 16 + ln) * 256 + lg * 8;
    const unsigned short* b1 = woutT + (size_t)((wv +  4) * 16 + ln) * 256 + lg * 8;
    const unsigned short* b2 = woutT + (size_t)((wv +  8) * 16 + ln) * 256 + lg * 8;
    const unsigned short* b3 = woutT + (size_t)((wv + 12) * 16 + ln) * 256 + lg * 8;
    bf16x8 bc0 = *reinterpret_cast<const bf16x8*>(b0);
    bf16x8 bc1 = *reinterpret_cast<const bf16x8*>(b1);
    bf16x8 bc2 = *reinterpret_cast<const bf16x8*>(b2);
    bf16x8 bc3 = *reinterpret_cast<const bf16x8*>(b3);

    #pragma unroll
    for (int it = 0; it < 8; ++it) {
        int idx = tid + (it << 8);
        int row = idx >> 5, c8 = idx & 31;
        const float* p = io + (m0 + row) * 256 + c8 * 8;
        float4 a = *reinterpret_cast<const float4*>(p);
        float4 b = *reinterpret_cast<const float4*>(p + 4);
        *reinterpret_cast<bf16x8*>(&sA[row][c8 * 8]) = cvt8(a, b);
    }
    __syncthreads();

    f32x4 acc[4][4];
    #pragma unroll
    for (int m = 0; m < 4; ++m)
        #pragma unroll
        for (int j = 0; j < 4; ++j) acc[m][j] = (f32x4)(0.f);

    #pragma unroll
    for (int st = 0; st < 8; ++st) {
        const int ko = st * 32 + lg * 8;
        bf16x8 a0 = *reinterpret_cast<const bf16x8*>(&sA[     ln][ko]);
        bf16x8 a1 = *reinterpret_cast<const bf16x8*>(&sA[16 + ln][ko]);
        bf16x8 a2 = *reinterpret_cast<const bf16x8*>(&sA[32 + ln][ko]);
        bf16x8 a3 = *reinterpret_cast<const bf16x8*>(&sA[48 + ln][ko]);
        bf16x8 bn0 = bc0, bn1 = bc1, bn2 = bc2, bn3 = bc3;
        if (st < 7) {
            bn0 = *reinterpret_cast<const bf16x8*>(b0 + (st + 1) * 32);
            bn1 = *reinterpret_cast<const bf16x8*>(b1 + (st + 1) * 32);
            bn2 = *reinterpret_cast<const bf16x8*>(b2 + (st + 1) * 32);
            bn3 = *reinterpret_cast<const bf16x8*>(b3 + (st + 1) * 32);
        }
        acc[0][0] = MFMA16(a0, bc0, acc[0][0], 0, 0, 0);
        acc[1][0] = MFMA16(a1, bc0, acc[1][0], 0, 0, 0);
        acc[2][0] = MFMA16(a2, bc0, acc[2][0], 0, 0, 0);
        acc[3][0] = MFMA16(a3, bc0, acc[3][0], 0, 0, 0);
        acc[0][1] = MFMA16(a0, bc1, acc[0][1], 0, 0, 0);
        acc[1][1] = MFMA16(a1, bc1, acc[1][1], 0, 0, 0);
        acc[2][1] = MFMA16(a2, bc1, acc[2][1], 0, 0, 0);
        acc[3][1] = MFMA16(a3, bc1, acc[3][1], 0, 0, 0);
        acc[0][2] = MFMA16(a0, bc2, acc[0][2], 0, 0, 0);
        acc[1][2] = MFMA16(a1, bc2, acc[1][2], 0, 0, 0);
        acc[2][2] = MFMA16(a2, bc2, acc[2][2], 0, 0, 0);
        acc[3][2] = MFMA16(a3, bc2, acc[3][2], 0, 0, 0);
        acc[0][3] = MFMA16(a0, bc3, acc[0][3], 0, 0, 0);
        acc[1][3] = MFMA16(a1, bc3, acc[1][3], 0, 0, 0);
        acc[2][3] = MFMA16(a2, bc3, acc[2][3], 0, 0, 0);
        acc[3][3] = MFMA16(a3, bc3, acc[3][3], 0, 0, 0);
        bc0 = bn0; bc1 = bn1; bc2 = bn2; bc3 = bn3;
    }

    #pragma unroll
    for (int j = 0; j < 4; ++j) {
        int nt = wv + 4 * j;
        float bias = b_out[nt * 16 + ln];
        #pragma unroll
        for (int m = 0; m < 4; ++m)
            #pragma unroll
            for (int r = 0; r < 4; ++r)
                io[(m0 + m * 16 + lg * 4 + r) * 256 + nt * 16 + ln] =
                    acc[m][j][r] + bias;
    }
}

extern "C" void kernel_launch(void* const* d_in, const int* in_sizes, int n_in,
                              void* d_out, int out_size, void* d_ws, size_t ws_size,
                              hipStream_t stream) {
    const float* x     = (const float*)d_in[0];
    const float* w_qkv = (const float*)d_in[1];
    const float* w_out = (const float*)d_in[2];
    const float* b_out = (const float*)d_in[3];
    const float* pe    = (const float*)d_in[4];
    (void)in_sizes; (void)n_in; (void)out_size;

    float* out = (float*)d_out;
    unsigned short* wsT = (unsigned short*)d_ws;
    float* bias_tab = (float*)((char*)d_ws + 524288);

    if (ws_size >= (size_t)WS3_NEED) {
        unsigned short* qkv = wsT + QKV_SHORT_OFF;
        prep_kernel<<<dim3(257),  dim3(256), 0, stream>>>(w_qkv, w_out, pe, wsT, bias_tab);
        qkv_gemm   <<<dim3(1024), dim3(256), 0, stream>>>(x, wsT, qkv);
        attn5      <<<dim3(8192), dim3(256), 0, stream>>>(qkv, bias_tab, out);
        proj4      <<<dim3(1024), dim3(256), 0, stream>>>(out, wsT + WOUTT_SHORT_OFF, b_out);
    } else {
        // ws >= WS_NEED (empirically true since round 4): fused fallback
        prep_kernel<<<dim3(257),  dim3(256), 0, stream>>>(w_qkv, w_out, pe, wsT, bias_tab);
        winattn4   <<<dim3(4096), dim3(256), 0, stream>>>(x, wsT, bias_tab, out);
        proj4      <<<dim3(1024), dim3(256), 0, stream>>>(out, wsT + WOUTT_SHORT_OFF, b_out);
    }
}